// Round 6
// baseline (1393.911 us; speedup 1.0000x reference)
//
#include <hip/hip_runtime.h>
#include <stdint.h>

#define BATCH 512
#define D_IN  2048
#define D_MCB 16000
#define N_OUT 3000

typedef __bf16 bf16x8 __attribute__((ext_vector_type(8)));
typedef __bf16 bf16x4 __attribute__((ext_vector_type(4)));
typedef _Float16 f16x8 __attribute__((ext_vector_type(8)));
typedef float  f32x4  __attribute__((ext_vector_type(4)));

// Native LDS float atomic add (fire-and-forget). addr = 32-bit LDS byte addr.
__device__ __forceinline__ void lds_fadd(unsigned addr, float v) {
    asm volatile("ds_add_f32 %0, %1" :: "v"(addr), "v"(v) : "memory");
}

// Async global->LDS, 16 bytes per lane (linear dest: base + lane*16).
__device__ __forceinline__ void gload16(const void* g, void* l) {
    __builtin_amdgcn_global_load_lds(
        (const __attribute__((address_space(1))) unsigned*)g,
        (__attribute__((address_space(3))) unsigned*)l,
        16, 0, 0);
}

// ---------------------------------------------------------------------------
// Kernel 1: count-sketch + circular convolution, GATHER with f16 p2 table.
//   z[b,k] = sum_i a1[b,i] * p2[b, (k + s_i) mod d],  s_i = d - h1[i]
// R9: chunk-grouped table layout replaces the XOR swizzle. Chunk c (8 f16
// elems) lives at phys slot p(c) = ((c&7)<<9) | (c>>3). Since a lane's chunk
// index is c = lane*8 + V + tt with V = wave*500 + csh WAVE-UNIFORM, the
// byte address is ((vt&7)<<13) + ((vt>>3)<<4) [SALU, uniform] + lane*16
// [precomputed] -> ONE v_add per chunk (was ~5 VALU of swizzle math), and
// each wave read is a contiguous 1024B block -> zero bank conflicts by
// construction. R8 measured ~240 VALU/iter, floor now ~81. f16 + fma_mix
// (R8) and dl-buckets (R7) retained. Numerics bitwise identical to R8.
// ---------------------------------------------------------------------------
__global__ __launch_bounds__(256, 2) void mcb_conv_kernel(
    const float* __restrict__ x0, const float* __restrict__ x1,
    const float* __restrict__ s1, const float* __restrict__ s2,
    const int* __restrict__ h1, const int* __restrict__ h2,
    __bf16* __restrict__ zb)
{
    __shared__ __align__(16) char smem[81920];
    unsigned short* p2x   = (unsigned short*)smem;         // [32768] f16 bits (ph4)
    float*          p2f   = (float*)smem;                  // [16000] fp32 overlay
    int*            cnt   = (int*)(smem + 64000);          // [8] bucket counts (pad region)
    int*            cur   = (int*)(smem + 64032);          // [8] cursors -> ends
    float2*         bdata = (float2*)(smem + 65536);       // [2048] bucketed (a1, s>>3)

    const int b    = blockIdx.x;
    const int t    = threadIdx.x;
    const int lane = t & 63;
    const int wave = t >> 6;

    // --- phase 1: zero p2f, zero counts, compute per-thread (a1, s) in regs ---
    if (t < 8) cnt[t] = 0;
    for (int k = t; k < D_MCB; k += 256) p2f[k] = 0.0f;

    float a1r[8];
    int   sr[8];
#pragma unroll
    for (int r = 0; r < 8; ++r) {
        int i  = t + 256 * r;
        a1r[r] = s1[i] * x0[(size_t)b * D_IN + i];
        sr[r]  = D_MCB - h1[i];                    // in [1, 16000]
    }
    __syncthreads();

    // --- phase 1b: bucket histogram + p2 scatter (overlapped) ---
#pragma unroll
    for (int r = 0; r < 8; ++r) atomicAdd(&cnt[sr[r] & 7], 1);
    for (int j = t; j < D_IN; j += 256) {
        float a2 = s2[j] * x1[(size_t)b * D_IN + j];
        lds_fadd((unsigned)(uintptr_t)&p2f[h2[j]], a2);
    }
    __syncthreads();

    if (t == 0) {
        int acc = 0;
        for (int d = 0; d < 8; ++d) { int c = cnt[d]; cur[d] = acc; acc += c; }
    }
    __syncthreads();

    // --- phase 1c: scatter (a1, s>>3) into bucketed order ---
#pragma unroll
    for (int r = 0; r < 8; ++r) {
        int slot = atomicAdd(&cur[sr[r] & 7], 1);
        bdata[slot] = make_float2(a1r[r], __int_as_float(sr[r] >> 3));
    }
    __syncthreads();
    // cur[d] is now the END index of bucket d; stash in regs before p2x
    // overwrites the pad region in phase 3.
    int ends[8];
#pragma unroll
    for (int d = 0; d < 8; ++d) ends[d] = cur[d];

    // --- phase 3: fp32 p2 -> f16 p2x, replicated to 32768 elems, stored
    //     chunk-grouped: chunk c -> phys slot ((c&7)<<9) | (c>>3).
    //     Register-staged (read all, barrier, write): p2x overlays p2f. ---
    f16x8 stage[16];
#pragma unroll
    for (int m = 0; m < 16; ++m) {
        int c  = t + 256 * m;                      // chunk in [0,4096)
        int e8 = c << 3;                           // elem base, [0,32768)
        if (e8 >= 2 * D_MCB) e8 -= 2 * D_MCB;
        else if (e8 >= D_MCB) e8 -= D_MCB;
        f32x4 lo = *(const f32x4*)(p2f + e8);
        f32x4 hi = *(const f32x4*)(p2f + e8 + 4);
        f16x8 o;
#pragma unroll
        for (int q = 0; q < 4; ++q) { o[q] = (_Float16)lo[q]; o[q + 4] = (_Float16)hi[q]; }
        stage[m] = o;
    }
    __syncthreads();
#pragma unroll
    for (int m = 0; m < 16; ++m) {
        int c  = t + 256 * m;
        int pc = ((c & 7) << 9) | (c >> 3);
        *(f16x8*)(p2x + pc * 8) = stage[m];
    }
    __syncthreads();

    // --- phase 4: gather over bucketed i's. Lane owns k in [k0, k0+64),
    //     wave w covers [4000w, 4000w+4096) (overlap masked at store). ---
    const int k0 = wave * 4000 + (lane << 6);      // multiple of 8
    const int W0 = wave * 500;                     // K8 = W0 + lane*8
    const int lane16 = lane << 4;
    const char* p2c = (const char*)smem;

    float zacc[64];
#pragma unroll
    for (int q = 0; q < 64; ++q) zacc[q] = 0.f;

    // Per i: 9 chunk loads at uniform-SALU + lane*16 addresses, then
    // 64 x v_fma_mix_f32 with compile-time delta D. Element e = q+D lives
    // in dword e>>1, half e&1; op_sel picks the f16 half (conversion free).
#define BUCKET(D, NC)                                                      \
    {                                                                      \
        const int end = __builtin_amdgcn_readfirstlane(ends[(D)]);         \
        for (; pos < end; ++pos) {                                         \
            float a1  = jd.x;                                              \
            int   csh = __float_as_int(jd.y);                              \
            jd = bdata[(pos + 1) & (D_IN - 1)];    /* broadcast prefetch */ \
            const int Vs = __builtin_amdgcn_readfirstlane(csh) + W0;       \
            uint4 w[9];                                                    \
            _Pragma("unroll")                                              \
            for (int tt = 0; tt < (NC); ++tt) {                            \
                int vt = Vs + tt;                                          \
                int S  = ((vt & 7) << 13) | ((vt >> 3) << 4);              \
                w[tt]  = *(const uint4*)(p2c + S + lane16);                \
            }                                                              \
            const unsigned* wd = (const unsigned*)w;                       \
            _Pragma("unroll")                                              \
            for (int q = 0; q < 64; ++q) {                                 \
                const int e = q + (D);                                     \
                unsigned dwv = wd[e >> 1];                                 \
                if (e & 1) {                                               \
                    asm("v_fma_mix_f32 %0, %1, %2, %0 op_sel:[0,1,0] op_sel_hi:[0,1,0]" \
                        : "+v"(zacc[q]) : "v"(a1), "v"(dwv));              \
                } else {                                                   \
                    asm("v_fma_mix_f32 %0, %1, %2, %0 op_sel:[0,0,0] op_sel_hi:[0,1,0]" \
                        : "+v"(zacc[q]) : "v"(a1), "v"(dwv));              \
                }                                                          \
            }                                                              \
        }                                                                  \
    }

    float2 jd = bdata[0];
    int pos = 0;
    BUCKET(0, 8)
    BUCKET(1, 9)
    BUCKET(2, 9)
    BUCKET(3, 9)
    BUCKET(4, 9)
    BUCKET(5, 9)
    BUCKET(6, 9)
    BUCKET(7, 9)
#undef BUCKET

    // --- store bf16 z, masking wave overlap (all bounds % 8 == 0) ---
    const int klim = wave * 4000 + 4000;
#pragma unroll
    for (int g = 0; g < 8; ++g) {
        int kg = k0 + g * 8;
        if (kg < klim) {
            bf16x8 o;
#pragma unroll
            for (int e = 0; e < 8; ++e) o[e] = (__bf16)zacc[g * 8 + e];
            *(bf16x8*)(zb + (size_t)b * D_MCB + kg) = o;
        }
    }
}

// ---------------------------------------------------------------------------
// Kernel 1.5: W fp32 -> bf16 pre-convert (one pass).
// ---------------------------------------------------------------------------
__global__ __launch_bounds__(256) void wconv_kernel(
    const float* __restrict__ W, __bf16* __restrict__ Wb)
{
    size_t i = ((size_t)blockIdx.x * 256 + threadIdx.x) * 4;
    f32x4 w = *(const f32x4*)(W + i);
    bf16x4 o;
#pragma unroll
    for (int q = 0; q < 4; ++q) o[q] = (__bf16)w[q];
    *(bf16x4*)(Wb + i) = o;
}

// ---------------------------------------------------------------------------
// Kernel 2: LDS-staged bf16 GEMM (R6 shape). BM=64 x BN=128, BK=64,
// grid = 192 1D XCD-swizzled (8 m-blocks sharing a Wb panel land on one
// XCD -> panel K-slices served by L2). 4 waves (2Mx2N), double-buffered
// LDS (48 KB), global_load_lds width=16, XOR chunk swizzle
// phys = c ^ (row&7). out = relu(z @ Wb^T + bias).
// ---------------------------------------------------------------------------
__global__ __launch_bounds__(256) void mcb_gemm_tiled_kernel(
    const __bf16* __restrict__ zbm, const __bf16* __restrict__ Wb,
    const float* __restrict__ bias, float* __restrict__ out)
{
    __shared__ __align__(16) char tile[49152];

    const int t    = threadIdx.x;
    const int lane = t & 63;
    const int wave = t >> 6;
    const int llo  = lane & 15;
    const int lhi  = lane >> 4;
    const int wm   = wave >> 1;            // 0..1 : M strip of 32
    const int wn   = wave & 1;             // 0..1 : N strip of 64

    // XCD swizzle decode: f = r + 8*(y + 8*a); x = 8a + r (n-block), y (m-block).
    const int f  = blockIdx.x;
    const int r  = f & 7;
    const int g  = f >> 3;
    const int yb = g & 7;
    const int xb = (g >> 3) * 8 + r;

    const int m0 = yb * 64;
    const int n0 = xb * 128;

    // --- staging: linear LDS dest, inverse-swizzled global source ---
    const __bf16* asrc[2];
    const __bf16* bsrc[4];
    int aoff[2], boff[4];
#pragma unroll
    for (int p = 0; p < 2; ++p) {
        int fb    = (p * 256 + t) * 16;    // byte offset in 8 KB A tile
        int row   = fb >> 7;               // 0..63 (128 B per row = 64 bf16)
        int physc = (fb >> 4) & 7;
        int logc  = physc ^ (row & 7);
        asrc[p] = zbm + (size_t)(m0 + row) * D_MCB + logc * 8;
        aoff[p] = fb;
    }
#pragma unroll
    for (int p = 0; p < 4; ++p) {
        int fb    = (p * 256 + t) * 16;    // byte offset in 16 KB B tile
        int row   = fb >> 7;               // 0..127
        int wrow  = n0 + row;
        if (wrow > N_OUT - 1) wrow = N_OUT - 1;   // clamp pad rows (masked at store)
        int physc = (fb >> 4) & 7;
        int logc  = physc ^ (row & 7);
        bsrc[p] = Wb + (size_t)wrow * D_MCB + logc * 8;
        boff[p] = 8192 + fb;
    }

#define STAGE(bufsel, kt)                                                  \
    {                                                                      \
        const int bo_ = (bufsel) * 24576;                                  \
        const int ke_ = (kt) * 64;                                         \
        _Pragma("unroll")                                                  \
        for (int p = 0; p < 2; ++p) gload16(asrc[p] + ke_, tile + bo_ + aoff[p]); \
        _Pragma("unroll")                                                  \
        for (int p = 0; p < 4; ++p) gload16(bsrc[p] + ke_, tile + bo_ + boff[p]); \
    }

    // --- fragment read offsets (swizzled) ---
    int ard[2][2], brd[4][2];
#pragma unroll
    for (int am = 0; am < 2; ++am)
#pragma unroll
        for (int ks = 0; ks < 2; ++ks) {
            int row = wm * 32 + am * 16 + llo;
            int c   = lhi + ks * 4;
            ard[am][ks] = row * 128 + (c ^ (row & 7)) * 16;
        }
#pragma unroll
    for (int bn = 0; bn < 4; ++bn)
#pragma unroll
        for (int ks = 0; ks < 2; ++ks) {
            int row = wn * 64 + bn * 16 + llo;
            int c   = lhi + ks * 4;
            brd[bn][ks] = 8192 + row * 128 + (c ^ (row & 7)) * 16;
        }

    f32x4 acc[2][4] = {};

    STAGE(0, 0);
    __syncthreads();

    int buf = 0;
    for (int kt = 0; kt < 250; ++kt) {
        if (kt + 1 < 250) STAGE(buf ^ 1, kt + 1);

        const char* base = tile + buf * 24576;
        bf16x8 a[2][2], bfr[4][2];
#pragma unroll
        for (int am = 0; am < 2; ++am)
#pragma unroll
            for (int ks = 0; ks < 2; ++ks)
                a[am][ks] = *(const bf16x8*)(base + ard[am][ks]);
#pragma unroll
        for (int bn = 0; bn < 4; ++bn)
#pragma unroll
            for (int ks = 0; ks < 2; ++ks)
                bfr[bn][ks] = *(const bf16x8*)(base + brd[bn][ks]);

#pragma unroll
        for (int ks = 0; ks < 2; ++ks)
#pragma unroll
            for (int am = 0; am < 2; ++am)
#pragma unroll
                for (int bn = 0; bn < 4; ++bn)
                    acc[am][bn] = __builtin_amdgcn_mfma_f32_16x16x32_bf16(
                        a[am][ks], bfr[bn][ks], acc[am][bn], 0, 0, 0);

        __syncthreads();
        buf ^= 1;
    }
#undef STAGE

    // --- epilogue: C/D layout col=lane&15, row=(lane>>4)*4+r ---
#pragma unroll
    for (int bn = 0; bn < 4; ++bn) {
        int col = n0 + wn * 64 + bn * 16 + llo;
        if (col < N_OUT) {
            float bv = bias[col];
#pragma unroll
            for (int am = 0; am < 2; ++am) {
                int rbase = m0 + wm * 32 + am * 16 + lhi * 4;
#pragma unroll
                for (int rr = 0; rr < 4; ++rr) {
                    float v = acc[am][bn][rr] + bv;
                    out[(size_t)(rbase + rr) * N_OUT + col] = v > 0.0f ? v : 0.0f;
                }
            }
        }
    }
}

// ---------------------------------------------------------------------------
// Kernel 2 (fallback): W stays fp32, converted in-register (no workspace).
// ---------------------------------------------------------------------------
__global__ __launch_bounds__(256) void mcb_gemm_f32_kernel(
    const __bf16* __restrict__ zbm, const float* __restrict__ W,
    const float* __restrict__ bias, float* __restrict__ out)
{
    const int lane = threadIdx.x & 63;
    const int wave = threadIdx.x >> 6;
    const int wm = wave >> 1;
    const int wn = wave & 1;
    const int llo = lane & 15;
    const int lhi = lane >> 4;

    const int m0 = blockIdx.y * 64 + wm * 32;
    const int n0 = blockIdx.x * 64 + wn * 32;

    f32x4 acc[2][2] = {};

    const int arow0 = m0 + llo;
    const int bcol0 = n0 + llo;
    const int kk = lhi * 8;

    const __bf16* aptr0 = zbm + (size_t)arow0 * D_MCB + kk;
    const __bf16* aptr1 = aptr0 + (size_t)16 * D_MCB;
    const float*  bptr0 = W + (size_t)bcol0 * D_MCB + kk;
    const float*  bptr1 = bptr0 + (size_t)16 * D_MCB;
    const bool bok0 = (bcol0 < N_OUT);
    const bool bok1 = (bcol0 + 16 < N_OUT);

    for (int k = 0; k < D_MCB; k += 32) {
        bf16x8 a0 = *(const bf16x8*)(aptr0 + k);
        bf16x8 a1 = *(const bf16x8*)(aptr1 + k);

        bf16x8 b0 = {}, b1 = {};
        if (bok0) {
            f32x4 w0 = *(const f32x4*)(bptr0 + k);
            f32x4 w1 = *(const f32x4*)(bptr0 + k + 4);
#pragma unroll
            for (int q = 0; q < 4; ++q) { b0[q] = (__bf16)w0[q]; b0[q + 4] = (__bf16)w1[q]; }
        }
        if (bok1) {
            f32x4 w0 = *(const f32x4*)(bptr1 + k);
            f32x4 w1 = *(const f32x4*)(bptr1 + k + 4);
#pragma unroll
            for (int q = 0; q < 4; ++q) { b1[q] = (__bf16)w0[q]; b1[q + 4] = (__bf16)w1[q]; }
        }

        acc[0][0] = __builtin_amdgcn_mfma_f32_16x16x32_bf16(a0, b0, acc[0][0], 0, 0, 0);
        acc[0][1] = __builtin_amdgcn_mfma_f32_16x16x32_bf16(a0, b1, acc[0][1], 0, 0, 0);
        acc[1][0] = __builtin_amdgcn_mfma_f32_16x16x32_bf16(a1, b0, acc[1][0], 0, 0, 0);
        acc[1][1] = __builtin_amdgcn_mfma_f32_16x16x32_bf16(a1, b1, acc[1][1], 0, 0, 0);
    }

#pragma unroll
    for (int bn = 0; bn < 2; ++bn) {
        int col = bcol0 + bn * 16;
        if (col >= N_OUT) continue;
        float bv = bias[col];
#pragma unroll
        for (int am = 0; am < 2; ++am) {
            int rbase = m0 + am * 16 + lhi * 4;
#pragma unroll
            for (int rr = 0; rr < 4; ++rr) {
                float v = acc[am][bn][rr] + bv;
                out[(size_t)(rbase + rr) * N_OUT + col] = v > 0.0f ? v : 0.0f;
            }
        }
    }
}

extern "C" void kernel_launch(void* const* d_in, const int* in_sizes, int n_in,
                              void* d_out, int out_size, void* d_ws, size_t ws_size,
                              hipStream_t stream) {
    // setup_inputs() order: x0, x1, s1, s2, W, b, h1, h2
    const float* x0   = (const float*)d_in[0];
    const float* x1   = (const float*)d_in[1];
    const float* s1   = (const float*)d_in[2];
    const float* s2   = (const float*)d_in[3];
    const float* W    = (const float*)d_in[4];
    const float* bias = (const float*)d_in[5];
    const int*   h1   = (const int*)d_in[6];
    const int*   h2   = (const int*)d_in[7];
    float* out = (float*)d_out;

    const size_t zb_bytes = (size_t)BATCH * D_MCB * sizeof(__bf16);   // 16,384,000
    const size_t wb_bytes = (size_t)N_OUT * D_MCB * sizeof(__bf16);   // 96,000,000

    __bf16* zbm = (__bf16*)d_ws;

    mcb_conv_kernel<<<BATCH, 256, 0, stream>>>(x0, x1, s1, s2, h1, h2, zbm);

    if (ws_size >= zb_bytes + wb_bytes) {
        __bf16* Wb = (__bf16*)((char*)d_ws + zb_bytes);
        wconv_kernel<<<46875, 256, 0, stream>>>(W, Wb);
        mcb_gemm_tiled_kernel<<<192, 256, 0, stream>>>(zbm, Wb, bias, out);
    } else {
        mcb_gemm_f32_kernel<<<dim3(47, 8), 256, 0, stream>>>(zbm, W, bias, out);
    }
}